// Round 10
// baseline (59.984 us; speedup 1.0000x reference)
//
#include <hip/hip_runtime.h>
#include <hip/hip_fp16.h>

#define BB 16
#define DD 512
#define NN 4096
#define KK 32
#define TNS 32          // n per subtile
#define SUBT 4          // subtiles per block (block owns 128 n)
#define NGRP 32         // n-groups (blocks) per batch
#define NBLK (BB*NGRP)  // 512 blocks
#define ROWX 40         // xbuf row stride (bf16 elems), 80 B
#define ROWA 40         // a_t row stride

// LDS byte offsets (total 77824 -> 2 blocks/CU)
#define OFF_XBUF 0              // bf16 [512][40] = 40960
#define OFF_CLDS 40960          // bf16 c swizzled [32][512] = 32768
#define OFF_AT   73728          // bf16 [32][40] = 2560
#define OFF_X2P  76288          // f32 [8][32] = 1024
#define OFF_S2   77312          // f32 [32]
#define OFF_C2   77440          // f32 [32]
#define OFF_ASUM 77568          // f32 [2][32]
#define LDS_TOTAL 77824

// xbuf layout: byte(d,n) = d*80 + ((n>>2) ^ ((d>>2)&7))*8 + (n&3)*2
// 8B half-chunk XOR swizzle -> bank spread carries through g for the
// phase-A column gather (the 16B/(d&3) scheme collapsed to 8 banks).

typedef unsigned short u16;
typedef __attribute__((ext_vector_type(8))) short short8v;
typedef __attribute__((ext_vector_type(4))) float f32x4;

#define SYNCL() asm volatile("s_waitcnt lgkmcnt(0)\n\ts_barrier" ::: "memory")

__device__ __forceinline__ unsigned f2bf(float f) {
    union { float f; unsigned u; } v; v.f = f;
    unsigned r = v.u + 0x7fff + ((v.u >> 16) & 1);   // RNE
    return r >> 16;
}

// ---------------- K1: fused, staggered staging, folded c-prep ------------
template <typename PART>
__global__ __launch_bounds__(512, 4)
void k1_fused(const float* __restrict__ x, const float* __restrict__ cw,
              const float* __restrict__ scale,
              float* __restrict__ ws_asum, PART* __restrict__ ws_e) {
    extern __shared__ char smem[];
    u16*   a_t     = (u16*)(smem + OFF_AT);
    float* x2_part = (float*)(smem + OFF_X2P);
    float* s2_l    = (float*)(smem + OFF_S2);
    float* c2_l    = (float*)(smem + OFF_C2);
    float* asum_p  = (float*)(smem + OFF_ASUM);
    u16*   c_lds   = (u16*)(smem + OFF_CLDS);

    const int t = threadIdx.x;
    const int l = t & 63, w = t >> 6;        // lane, wave (8 waves)
    const int g = l >> 4, li = l & 15;       // 16-lane group, group-lane
    const int blk = blockIdx.x;
    const int b = blk >> 5, grp = blk & 31;
    const int n0 = grp * 128;
    const float* xg = x + (size_t)b * DD * NN + n0;

    // staging geometry: wave w owns rows [64w, 64w+64)
    const int lr = l >> 3;                   // row-subgroup 0..7
    const int lc = l & 7;                    // 16B fp32 col-group (4 n)
    const float* xrow = xg + (size_t)(w * 64 + lr) * NN + lc * 4;

    // ---- prologue: c-row loads first ----
    const int ck = t >> 4, cseg = t & 15;    // 16 threads per k-row
    float4 cv[8];
    {
        const float* crow = cw + ck * DD + cseg * 32;
#pragma unroll
        for (int j = 0; j < 8; ++j) cv[j] = *(const float4*)(crow + 4 * j);
    }

    // ---- issue subtile-0 x loads (two halves) ----
    float4 vaA[4], vaB[4];
#pragma unroll
    for (int j = 0; j < 4; ++j) vaA[j] = *(const float4*)(xrow + (size_t)(j * 8) * NN);
#pragma unroll
    for (int j = 0; j < 4; ++j) vaB[j] = *(const float4*)(xrow + (size_t)((j + 4) * 8) * NN);

    // ---- stage c -> c_lds (chunk-swizzled) + c2 via 16-lane reduce ----
    {
        float c2p = 0.f;
#pragma unroll
        for (int j = 0; j < 8; ++j)
            c2p += cv[j].x * cv[j].x + cv[j].y * cv[j].y
                 + cv[j].z * cv[j].z + cv[j].w * cv[j].w;
#pragma unroll
        for (int j = 0; j < 4; ++j) {
            uint4 pk;
            asm("v_cvt_pk_bf16_f32 %0, %1, %2" : "=v"(pk.x) : "v"(cv[2*j].x),   "v"(cv[2*j].y));
            asm("v_cvt_pk_bf16_f32 %0, %1, %2" : "=v"(pk.y) : "v"(cv[2*j].z),   "v"(cv[2*j].w));
            asm("v_cvt_pk_bf16_f32 %0, %1, %2" : "=v"(pk.z) : "v"(cv[2*j+1].x), "v"(cv[2*j+1].y));
            asm("v_cvt_pk_bf16_f32 %0, %1, %2" : "=v"(pk.w) : "v"(cv[2*j+1].z), "v"(cv[2*j+1].w));
            const int dch = cseg * 4 + j;                 // 16B chunk idx 0..63
            *(uint4*)(smem + OFF_CLDS + ck * 1024 + ((dch ^ (ck & 7)) << 4)) = pk;
        }
        c2p += __shfl_xor(c2p, 1); c2p += __shfl_xor(c2p, 2);
        c2p += __shfl_xor(c2p, 4); c2p += __shfl_xor(c2p, 8);
        if ((l & 15) == 0) c2_l[ck] = c2p;
        if (t < KK) { float sc = scale[t]; s2_l[t] = sc * sc; }
    }

    f32x4 accB[8];
#pragma unroll
    for (int dt = 0; dt < 8; ++dt) accB[dt] = (f32x4){0.f, 0.f, 0.f, 0.f};
    float asum_acc[8] = {0.f, 0.f, 0.f, 0.f, 0.f, 0.f, 0.f, 0.f};

#pragma unroll
    for (int s = 0; s < SUBT; ++s) {
        // ---- convert vaA/vaB -> xbuf (swizzled b64 writes) + x2 partials ----
        {
            float p0 = 0, p1 = 0, p2 = 0, p3 = 0;
#pragma unroll
            for (int j = 0; j < 8; ++j) {
                float4 v = (j < 4) ? vaA[j] : vaB[j - 4];
                uint2 pk;
                asm("v_cvt_pk_bf16_f32 %0, %1, %2" : "=v"(pk.x) : "v"(v.x), "v"(v.y));
                asm("v_cvt_pk_bf16_f32 %0, %1, %2" : "=v"(pk.y) : "v"(v.z), "v"(v.w));
                const int r = w * 64 + j * 8 + lr;
                const int hc = lc ^ ((j * 2 + (lr >> 2)) & 7);   // (r>>2)&7 sans w*16
                *(uint2*)(smem + OFF_XBUF + r * 80 + hc * 8) = pk;
                p0 += v.x * v.x; p1 += v.y * v.y;
                p2 += v.z * v.z; p3 += v.w * v.w;
            }
            p0 += __shfl_xor(p0, 8); p0 += __shfl_xor(p0, 16); p0 += __shfl_xor(p0, 32);
            p1 += __shfl_xor(p1, 8); p1 += __shfl_xor(p1, 16); p1 += __shfl_xor(p1, 32);
            p2 += __shfl_xor(p2, 8); p2 += __shfl_xor(p2, 16); p2 += __shfl_xor(p2, 32);
            p3 += __shfl_xor(p3, 8); p3 += __shfl_xor(p3, 16); p3 += __shfl_xor(p3, 32);
            if (lr == 0) {
                float4 p4 = {p0, p1, p2, p3};
                *(float4*)((char*)smem + OFF_X2P + w * 128 + lc * 16) = p4;
            }
        }
        SYNCL();   // 1: xbuf + x2_part visible (also gates c_lds/c2/s2 at s=0)

        // ---- issue next subtile's first-half loads (all waves, early) ----
        if (s < SUBT - 1) {
#pragma unroll
            for (int j = 0; j < 4; ++j)
                vaA[j] = *(const float4*)(xrow + (size_t)(j * 8) * NN + (s + 1) * TNS);
        }

        // ---- phase A + softmax fused (waves 0-1, boosted priority) ----
        if (w < 2) {
            __builtin_amdgcn_s_setprio(1);
            f32x4 accA0 = {0.f, 0.f, 0.f, 0.f}, accA1 = {0.f, 0.f, 0.f, 0.f};
            const int nloc = w * 16 + li;
            const int nh = nloc >> 2;            // half-chunk id of our column
            const int nb = (li & 3) * 2;         // byte offset within half-chunk
            for (int ch = 0; ch < 16; ++ch) {
                const int dbase = ch * 32 + g * 8;
                short8v bf;
#pragma unroll
                for (int j = 0; j < 8; ++j) {
                    const int d = dbase + j;
                    const int sD = (g * 2 + (j >> 2)) & 7;   // (d>>2)&7, ch*8 drops
                    bf[j] = *(const short*)(smem + OFF_XBUF + d * 80 + ((nh ^ sD) << 3) + nb);
                }
                const int csw = ((ch * 4 + g) ^ (li & 7)) << 3;
                short8v a0 = *(const short8v*)(c_lds + li * DD + csw);
                short8v a1 = *(const short8v*)(c_lds + (16 + li) * DD + csw);
                accA0 = __builtin_amdgcn_mfma_f32_16x16x32_bf16(a0, bf, accA0, 0, 0, 0);
                accA1 = __builtin_amdgcn_mfma_f32_16x16x32_bf16(a1, bf, accA1, 0, 0, 0);
            }
            // softmax over k for column nloc
            float x2v = 0.f;
#pragma unroll
            for (int p = 0; p < 8; ++p) x2v += x2_part[p * 32 + nloc];
            float sl[8];
            float mx = -3.4e38f;
#pragma unroll
            for (int r = 0; r < 4; ++r) {
                float v0 = s2_l[4 * g + r]      * (x2v - 2.f * accA0[r] + c2_l[4 * g + r]);
                float v1 = s2_l[16 + 4 * g + r] * (x2v - 2.f * accA1[r] + c2_l[16 + 4 * g + r]);
                sl[r] = v0; sl[4 + r] = v1;
                mx = fmaxf(mx, fmaxf(v0, v1));
            }
            mx = fmaxf(mx, __shfl_xor(mx, 16));
            mx = fmaxf(mx, __shfl_xor(mx, 32));
            float sum = 0.f;
#pragma unroll
            for (int i = 0; i < 8; ++i) { sl[i] = __expf(sl[i] - mx); sum += sl[i]; }
            sum += __shfl_xor(sum, 16);
            sum += __shfl_xor(sum, 32);
            const float inv = 1.f / sum;
#pragma unroll
            for (int i = 0; i < 8; ++i) {
                float a = sl[i] * inv;
                int k = (i < 4) ? (4 * g + i) : (16 + 4 * g + (i - 4));
                a_t[k * ROWA + nloc] = (u16)f2bf(a);
                float ssum = a;
                ssum += __shfl_xor(ssum, 1); ssum += __shfl_xor(ssum, 2);
                ssum += __shfl_xor(ssum, 4); ssum += __shfl_xor(ssum, 8);
                asum_acc[i] += ssum;    // valid on li==0
            }
            __builtin_amdgcn_s_setprio(0);
        }

        // ---- issue next subtile's second-half loads (staggered) ----
        if (s < SUBT - 1) {
#pragma unroll
            for (int j = 0; j < 4; ++j)
                vaB[j] = *(const float4*)(xrow + (size_t)((j + 4) * 8) * NN + (s + 1) * TNS);
        }
        SYNCL();   // 2: a_t ready

        // ---- phase B (all 8 waves): e[k-tile][128 d per wave] += a . x^T ----
        {
            const int kt = w >> 2, dblk = w & 3;
            short8v af = *(const short8v*)(a_t + (kt * 16 + li) * ROWA + g * 8);
#pragma unroll
            for (int dt = 0; dt < 8; ++dt) {
                const int d = dblk * 128 + dt * 16 + li;
                const int sD = (dt * 4 + (li >> 2)) & 7;     // (d>>2)&7, dblk*32 drops
                const char* base = smem + OFF_XBUF + d * 80;
                union { uint2 u2[2]; short8v v; } uu;
                uu.u2[0] = *(const uint2*)(base + (((g * 2)     ^ sD) << 3));
                uu.u2[1] = *(const uint2*)(base + (((g * 2 + 1) ^ sD) << 3));
                accB[dt] = __builtin_amdgcn_mfma_f32_16x16x32_bf16(af, uu.v, accB[dt], 0, 0, 0);
            }
        }
        SYNCL();   // 3: xbuf free for next convert
    }

    // ---- asum -> ws ----
    if (w < 2 && li == 0) {
#pragma unroll
        for (int i = 0; i < 8; ++i) {
            int k = (i < 4) ? (4 * g + i) : (16 + 4 * g + (i - 4));
            asum_p[w * KK + k] = asum_acc[i];
        }
    }
    __syncthreads();
    if (t < KK) ws_asum[(size_t)blk * KK + t] = asum_p[t] + asum_p[KK + t];

    // ---- e partials -> ws (once per block) ----
    {
        const int kt = w >> 2, dblk = w & 3;
        const size_t ebase = (size_t)blk * KK * DD;
#pragma unroll
        for (int dt = 0; dt < 8; ++dt)
#pragma unroll
            for (int r = 0; r < 4; ++r) {
                int k = kt * 16 + 4 * g + r;
                int d = dblk * 128 + dt * 16 + li;
                ws_e[ebase + (size_t)k * DD + d] = (PART)(accB[dt][r]);
            }
    }
}

// ---------------- K2: reduce 32 partials, subtract asum*c ----------------
__global__ void k2_reduce_h(const __half2* __restrict__ ws_e, const float* __restrict__ ws_asum,
                            const float* __restrict__ cw, float* __restrict__ out) {
    int tid = blockIdx.x * blockDim.x + threadIdx.x;   // 131072
    int d2 = tid & 255;
    int k = (tid >> 8) & (KK - 1);
    int b = tid >> 13;
    const __half2* pe = ws_e + ((size_t)(b * NGRP) * KK + k) * 256 + d2;
    const float* pa = ws_asum + b * NGRP * KK + k;
    float s0 = 0.f, s1 = 0.f, as = 0.f;
#pragma unroll
    for (int tl = 0; tl < NGRP; ++tl) {
        float2 f = __half22float2(pe[(size_t)tl * KK * 256]);
        s0 += f.x; s1 += f.y;
        as += pa[tl * KK];
    }
    int d = d2 * 2;
    float c0 = cw[k * DD + d], c1 = cw[k * DD + d + 1];
    float2 o; o.x = s0 - as * c0; o.y = s1 - as * c1;
    *(float2*)(out + ((size_t)(b * KK + k) * DD + d)) = o;
}

__global__ void k2_reduce_f(const float* __restrict__ ws_e, const float* __restrict__ ws_asum,
                            const float* __restrict__ cw, float* __restrict__ out) {
    int tid = blockIdx.x * blockDim.x + threadIdx.x;   // 262144
    int d = tid & (DD - 1);
    int k = (tid >> 9) & (KK - 1);
    int b = tid >> 14;
    float s = 0.f, as = 0.f;
#pragma unroll
    for (int tl = 0; tl < NGRP; ++tl) {
        int blk = b * NGRP + tl;
        s += ws_e[((size_t)blk * KK + k) * DD + d];
        as += ws_asum[(size_t)blk * KK + k];
    }
    out[tid] = s - as * cw[k * DD + d];
}

extern "C" void kernel_launch(void* const* d_in, const int* in_sizes, int n_in,
                              void* d_out, int out_size, void* d_ws, size_t ws_size,
                              hipStream_t stream) {
    const float* x = (const float*)d_in[0];
    const float* cw = (const float*)d_in[1];
    const float* scale = (const float*)d_in[2];
    float* out = (float*)d_out;

    char* ws = (char*)d_ws;
    float* ws_asum = (float*)ws;                // 512*32*4 = 65536 B
    char*  e_ptr   = ws + 65536;

    const size_t need_h = 65536 + (size_t)NBLK * KK * DD * sizeof(__half);

    if (ws_size >= need_h) {
        k1_fused<__half><<<NBLK, 512, LDS_TOTAL, stream>>>(x, cw, scale, ws_asum, (__half*)e_ptr);
        k2_reduce_h<<<(BB * KK * 256) / 256, 256, 0, stream>>>((const __half2*)e_ptr, ws_asum, cw, out);
    } else {
        k1_fused<float><<<NBLK, 512, LDS_TOTAL, stream>>>(x, cw, scale, ws_asum, (float*)e_ptr);
        k2_reduce_f<<<(BB * KK * DD) / 256, 256, 0, stream>>>((const float*)e_ptr, ws_asum, cw, out);
    }
}

// Round 11
// 52.154 us; speedup vs baseline: 1.1501x; 1.1501x over previous
//
#include <hip/hip_runtime.h>
#include <hip/hip_fp16.h>

#define BB 16
#define DD 512
#define NN 4096
#define KK 32
#define TNS 32          // n per subtile
#define SUBT 4          // subtiles per block (block owns 128 n)
#define NGRP 32         // n-groups (blocks) per batch
#define NBLK (BB*NGRP)  // 512 blocks
#define ROWX 40         // xbuf row stride (bf16 elems), 80 B
#define ROWA 40         // a_t row stride

// LDS byte offsets (total 77824 -> 2 blocks/CU)
#define OFF_XBUF 0              // bf16 [512][40] = 40960
#define OFF_CLDS 40960          // bf16 c swizzled [32][512] = 32768
#define OFF_AT   73728          // bf16 [32][40] = 2560
#define OFF_X2P  76288          // f32 [8][32] = 1024
#define OFF_S2   77312          // f32 [32]
#define OFF_C2   77440          // f32 [32]
#define OFF_ASUM 77568          // f32 [2][32]
#define LDS_TOTAL 77824

// xbuf layout: byte(d,n) = d*80 + (((n>>3) ^ (d&3) ^ ((d>>3)&3))<<4) + (n&7)*2
// The ((d>>3)&3) term injects the MFMA-group bit so phase-A's column gather
// (d = ch*32 + g*8 + j across lanes) spans all 4 chunks -> conflict-free.
// All accesses stay 16B-granular: b64 writes, b128 phase-B reads. No unions.

typedef unsigned short u16;
typedef __attribute__((ext_vector_type(8))) short short8v;
typedef __attribute__((ext_vector_type(4))) float f32x4;

#define SYNCL() asm volatile("s_waitcnt lgkmcnt(0)\n\ts_barrier" ::: "memory")

__device__ __forceinline__ unsigned f2bf(float f) {
    union { float f; unsigned u; } v; v.f = f;
    unsigned r = v.u + 0x7fff + ((v.u >> 16) & 1);   // RNE
    return r >> 16;
}

// ---------------- K1: fused, staggered staging, folded c-prep ------------
template <typename PART>
__global__ __launch_bounds__(512, 4)
void k1_fused(const float* __restrict__ x, const float* __restrict__ cw,
              const float* __restrict__ scale,
              float* __restrict__ ws_asum, PART* __restrict__ ws_e) {
    extern __shared__ char smem[];
    u16*   xbuf    = (u16*)(smem + OFF_XBUF);
    u16*   c_lds   = (u16*)(smem + OFF_CLDS);
    u16*   a_t     = (u16*)(smem + OFF_AT);
    float* x2_part = (float*)(smem + OFF_X2P);
    float* s2_l    = (float*)(smem + OFF_S2);
    float* c2_l    = (float*)(smem + OFF_C2);
    float* asum_p  = (float*)(smem + OFF_ASUM);

    const int t = threadIdx.x;
    const int l = t & 63, w = t >> 6;        // lane, wave (8 waves)
    const int g = l >> 4, li = l & 15;       // 16-lane group, group-lane
    const int blk = blockIdx.x;
    const int b = blk >> 5, grp = blk & 31;
    const int n0 = grp * 128;
    const float* xg = x + (size_t)b * DD * NN + n0;

    // staging geometry: wave w owns rows [64w, 64w+64)
    const int lr = l >> 3;                   // row-subgroup 0..7
    const int lc = l & 7;                    // 16B fp32 col-group (4 n)
    const int cp = lc >> 1, lo = lc & 1;     // chunk + 8B half within chunk
    const float* xrow = xg + (size_t)(w * 64 + lr) * NN + lc * 4;

    // ---- prologue: c-row loads first ----
    const int ck = t >> 4, cseg = t & 15;    // 16 threads per k-row
    float4 cv[8];
    {
        const float* crow = cw + ck * DD + cseg * 32;
#pragma unroll
        for (int j = 0; j < 8; ++j) cv[j] = *(const float4*)(crow + 4 * j);
    }

    // ---- issue subtile-0 x loads (two halves) ----
    float4 vaA[4], vaB[4];
#pragma unroll
    for (int j = 0; j < 4; ++j) vaA[j] = *(const float4*)(xrow + (size_t)(j * 8) * NN);
#pragma unroll
    for (int j = 0; j < 4; ++j) vaB[j] = *(const float4*)(xrow + (size_t)((j + 4) * 8) * NN);

    // ---- stage c -> c_lds (chunk-swizzled) + c2 via 16-lane reduce ----
    {
        float c2p = 0.f;
#pragma unroll
        for (int j = 0; j < 8; ++j)
            c2p += cv[j].x * cv[j].x + cv[j].y * cv[j].y
                 + cv[j].z * cv[j].z + cv[j].w * cv[j].w;
#pragma unroll
        for (int j = 0; j < 4; ++j) {
            uint4 pk;
            asm("v_cvt_pk_bf16_f32 %0, %1, %2" : "=v"(pk.x) : "v"(cv[2*j].x),   "v"(cv[2*j].y));
            asm("v_cvt_pk_bf16_f32 %0, %1, %2" : "=v"(pk.y) : "v"(cv[2*j].z),   "v"(cv[2*j].w));
            asm("v_cvt_pk_bf16_f32 %0, %1, %2" : "=v"(pk.z) : "v"(cv[2*j+1].x), "v"(cv[2*j+1].y));
            asm("v_cvt_pk_bf16_f32 %0, %1, %2" : "=v"(pk.w) : "v"(cv[2*j+1].z), "v"(cv[2*j+1].w));
            const int dch = cseg * 4 + j;                 // 16B chunk idx 0..63
            *(uint4*)(smem + OFF_CLDS + ck * 1024 + ((dch ^ (ck & 7)) << 4)) = pk;
        }
        c2p += __shfl_xor(c2p, 1); c2p += __shfl_xor(c2p, 2);
        c2p += __shfl_xor(c2p, 4); c2p += __shfl_xor(c2p, 8);
        if ((l & 15) == 0) c2_l[ck] = c2p;
        if (t < KK) { float sc = scale[t]; s2_l[t] = sc * sc; }
    }

    f32x4 accB[8];
#pragma unroll
    for (int dt = 0; dt < 8; ++dt) accB[dt] = (f32x4){0.f, 0.f, 0.f, 0.f};
    float asum_acc[8] = {0.f, 0.f, 0.f, 0.f, 0.f, 0.f, 0.f, 0.f};

#pragma unroll
    for (int s = 0; s < SUBT; ++s) {
        // ---- convert vaA/vaB -> xbuf (swizzled b64 writes) + x2 partials ----
        {
            float p0 = 0, p1 = 0, p2 = 0, p3 = 0;
#pragma unroll
            for (int j = 0; j < 8; ++j) {
                float4 v = (j < 4) ? vaA[j] : vaB[j - 4];
                uint2 pk;
                asm("v_cvt_pk_bf16_f32 %0, %1, %2" : "=v"(pk.x) : "v"(v.x), "v"(v.y));
                asm("v_cvt_pk_bf16_f32 %0, %1, %2" : "=v"(pk.y) : "v"(v.z), "v"(v.w));
                const int r = w * 64 + j * 8 + lr;
                // chunk = cp ^ (r&3) ^ ((r>>3)&3) = cp ^ (lr&3) ^ (j&3)
                const int hc = ((cp ^ (lr & 3) ^ (j & 3)) << 4) | (lo << 3);
                *(uint2*)(smem + OFF_XBUF + r * 80 + hc) = pk;
                p0 += v.x * v.x; p1 += v.y * v.y;
                p2 += v.z * v.z; p3 += v.w * v.w;
            }
            p0 += __shfl_xor(p0, 8); p0 += __shfl_xor(p0, 16); p0 += __shfl_xor(p0, 32);
            p1 += __shfl_xor(p1, 8); p1 += __shfl_xor(p1, 16); p1 += __shfl_xor(p1, 32);
            p2 += __shfl_xor(p2, 8); p2 += __shfl_xor(p2, 16); p2 += __shfl_xor(p2, 32);
            p3 += __shfl_xor(p3, 8); p3 += __shfl_xor(p3, 16); p3 += __shfl_xor(p3, 32);
            if (lr == 0) {
                float4 p4 = {p0, p1, p2, p3};
                *(float4*)((char*)smem + OFF_X2P + w * 128 + lc * 16) = p4;
            }
        }
        SYNCL();   // 1: xbuf + x2_part visible (also gates c_lds/c2/s2 at s=0)

        // ---- issue next subtile's first-half loads (all waves, early) ----
        if (s < SUBT - 1) {
#pragma unroll
            for (int j = 0; j < 4; ++j)
                vaA[j] = *(const float4*)(xrow + (size_t)(j * 8) * NN + (s + 1) * TNS);
        }

        // ---- phase A + softmax fused (waves 0-1, boosted priority) ----
        if (w < 2) {
            __builtin_amdgcn_s_setprio(1);
            f32x4 accA0 = {0.f, 0.f, 0.f, 0.f}, accA1 = {0.f, 0.f, 0.f, 0.f};
            const int nloc = w * 16 + li;
            const int ncg = (nloc >> 3) ^ g;     // chunk base: nc ^ g
            const int nr = nloc & 7;
            for (int ch = 0; ch < 16; ++ch) {
                const int dbase = ch * 32 + g * 8;
                short8v bf;
#pragma unroll
                for (int j = 0; j < 8; ++j) {
                    const int d = dbase + j;
                    // chunk = nc ^ (d&3) ^ ((d>>3)&3) = nc ^ (j&3) ^ g
                    bf[j] = (short)xbuf[d * ROWX + ((ncg ^ (j & 3)) << 3) + nr];
                }
                const int csw = ((ch * 4 + g) ^ (li & 7)) << 3;
                short8v a0 = *(const short8v*)(c_lds + li * DD + csw);
                short8v a1 = *(const short8v*)(c_lds + (16 + li) * DD + csw);
                accA0 = __builtin_amdgcn_mfma_f32_16x16x32_bf16(a0, bf, accA0, 0, 0, 0);
                accA1 = __builtin_amdgcn_mfma_f32_16x16x32_bf16(a1, bf, accA1, 0, 0, 0);
            }
            // softmax over k for column nloc
            float x2v = 0.f;
#pragma unroll
            for (int p = 0; p < 8; ++p) x2v += x2_part[p * 32 + nloc];
            float sl[8];
            float mx = -3.4e38f;
#pragma unroll
            for (int r = 0; r < 4; ++r) {
                float v0 = s2_l[4 * g + r]      * (x2v - 2.f * accA0[r] + c2_l[4 * g + r]);
                float v1 = s2_l[16 + 4 * g + r] * (x2v - 2.f * accA1[r] + c2_l[16 + 4 * g + r]);
                sl[r] = v0; sl[4 + r] = v1;
                mx = fmaxf(mx, fmaxf(v0, v1));
            }
            mx = fmaxf(mx, __shfl_xor(mx, 16));
            mx = fmaxf(mx, __shfl_xor(mx, 32));
            float sum = 0.f;
#pragma unroll
            for (int i = 0; i < 8; ++i) { sl[i] = __expf(sl[i] - mx); sum += sl[i]; }
            sum += __shfl_xor(sum, 16);
            sum += __shfl_xor(sum, 32);
            const float inv = 1.f / sum;
#pragma unroll
            for (int i = 0; i < 8; ++i) {
                float a = sl[i] * inv;
                int k = (i < 4) ? (4 * g + i) : (16 + 4 * g + (i - 4));
                a_t[k * ROWA + nloc] = (u16)f2bf(a);
                float ssum = a;
                ssum += __shfl_xor(ssum, 1); ssum += __shfl_xor(ssum, 2);
                ssum += __shfl_xor(ssum, 4); ssum += __shfl_xor(ssum, 8);
                asum_acc[i] += ssum;    // valid on li==0
            }
            __builtin_amdgcn_s_setprio(0);
        }

        // ---- issue next subtile's second-half loads (staggered) ----
        if (s < SUBT - 1) {
#pragma unroll
            for (int j = 0; j < 4; ++j)
                vaB[j] = *(const float4*)(xrow + (size_t)((j + 4) * 8) * NN + (s + 1) * TNS);
        }
        SYNCL();   // 2: a_t ready

        // ---- phase B (all 8 waves): e[k-tile][128 d per wave] += a . x^T ----
        {
            const int kt = w >> 2, dblk = w & 3;
            short8v af = *(const short8v*)(a_t + (kt * 16 + li) * ROWA + g * 8);
            // chunk = g ^ (d&3) ^ ((d>>3)&3); d = dblk*128 + dt*16 + li
            const int sB0 = g ^ (li & 3);
#pragma unroll
            for (int dt = 0; dt < 8; ++dt) {
                const int d = dblk * 128 + dt * 16 + li;
                const int chnk = sB0 ^ ((dt * 2 + (li >> 3)) & 3);
                short8v xf = *(const short8v*)(xbuf + d * ROWX + (chnk << 3));
                accB[dt] = __builtin_amdgcn_mfma_f32_16x16x32_bf16(af, xf, accB[dt], 0, 0, 0);
            }
        }
        SYNCL();   // 3: xbuf free for next convert
    }

    // ---- asum -> ws ----
    if (w < 2 && li == 0) {
#pragma unroll
        for (int i = 0; i < 8; ++i) {
            int k = (i < 4) ? (4 * g + i) : (16 + 4 * g + (i - 4));
            asum_p[w * KK + k] = asum_acc[i];
        }
    }
    __syncthreads();
    if (t < KK) ws_asum[(size_t)blk * KK + t] = asum_p[t] + asum_p[KK + t];

    // ---- e partials -> ws (once per block) ----
    {
        const int kt = w >> 2, dblk = w & 3;
        const size_t ebase = (size_t)blk * KK * DD;
#pragma unroll
        for (int dt = 0; dt < 8; ++dt)
#pragma unroll
            for (int r = 0; r < 4; ++r) {
                int k = kt * 16 + 4 * g + r;
                int d = dblk * 128 + dt * 16 + li;
                ws_e[ebase + (size_t)k * DD + d] = (PART)(accB[dt][r]);
            }
    }
}

// ---------------- K2: reduce 32 partials, subtract asum*c ----------------
__global__ void k2_reduce_h(const __half2* __restrict__ ws_e, const float* __restrict__ ws_asum,
                            const float* __restrict__ cw, float* __restrict__ out) {
    int tid = blockIdx.x * blockDim.x + threadIdx.x;   // 131072
    int d2 = tid & 255;
    int k = (tid >> 8) & (KK - 1);
    int b = tid >> 13;
    const __half2* pe = ws_e + ((size_t)(b * NGRP) * KK + k) * 256 + d2;
    const float* pa = ws_asum + b * NGRP * KK + k;
    float s0 = 0.f, s1 = 0.f, as = 0.f;
#pragma unroll
    for (int tl = 0; tl < NGRP; ++tl) {
        float2 f = __half22float2(pe[(size_t)tl * KK * 256]);
        s0 += f.x; s1 += f.y;
        as += pa[tl * KK];
    }
    int d = d2 * 2;
    float c0 = cw[k * DD + d], c1 = cw[k * DD + d + 1];
    float2 o; o.x = s0 - as * c0; o.y = s1 - as * c1;
    *(float2*)(out + ((size_t)(b * KK + k) * DD + d)) = o;
}

__global__ void k2_reduce_f(const float* __restrict__ ws_e, const float* __restrict__ ws_asum,
                            const float* __restrict__ cw, float* __restrict__ out) {
    int tid = blockIdx.x * blockDim.x + threadIdx.x;   // 262144
    int d = tid & (DD - 1);
    int k = (tid >> 9) & (KK - 1);
    int b = tid >> 14;
    float s = 0.f, as = 0.f;
#pragma unroll
    for (int tl = 0; tl < NGRP; ++tl) {
        int blk = b * NGRP + tl;
        s += ws_e[((size_t)blk * KK + k) * DD + d];
        as += ws_asum[(size_t)blk * KK + k];
    }
    out[tid] = s - as * cw[k * DD + d];
}

extern "C" void kernel_launch(void* const* d_in, const int* in_sizes, int n_in,
                              void* d_out, int out_size, void* d_ws, size_t ws_size,
                              hipStream_t stream) {
    const float* x = (const float*)d_in[0];
    const float* cw = (const float*)d_in[1];
    const float* scale = (const float*)d_in[2];
    float* out = (float*)d_out;

    char* ws = (char*)d_ws;
    float* ws_asum = (float*)ws;                // 512*32*4 = 65536 B
    char*  e_ptr   = ws + 65536;

    const size_t need_h = 65536 + (size_t)NBLK * KK * DD * sizeof(__half);

    if (ws_size >= need_h) {
        k1_fused<__half><<<NBLK, 512, LDS_TOTAL, stream>>>(x, cw, scale, ws_asum, (__half*)e_ptr);
        k2_reduce_h<<<(BB * KK * 256) / 256, 256, 0, stream>>>((const __half2*)e_ptr, ws_asum, cw, out);
    } else {
        k1_fused<float><<<NBLK, 512, LDS_TOTAL, stream>>>(x, cw, scale, ws_asum, (float*)e_ptr);
        k2_reduce_f<<<(BB * KK * DD) / 256, 256, 0, stream>>>((const float*)e_ptr, ws_asum, cw, out);
    }
}

// Round 12
// 38.566 us; speedup vs baseline: 1.5554x; 1.3523x over previous
//
#include <hip/hip_runtime.h>
#include <hip/hip_fp16.h>

#define BB 16
#define DD 512
#define NN 4096
#define KK 32
#define TNS 32          // n per subtile
#define SUBT 4          // subtiles per block (block owns 128 n)
#define NGRP 32         // n-groups (blocks) per batch
#define NBLK (BB*NGRP)  // 512 blocks
#define ROWX 40         // xbuf row stride (bf16 elems), 80 B
#define ROWA 40         // a_t row stride

// LDS byte offsets (total 77824 -> 2 blocks/CU)
#define OFF_XBUF 0              // bf16 [512][40] = 40960
#define OFF_CLDS 40960          // bf16 c swizzled [32][512] = 32768
#define OFF_AT   73728          // bf16 [32][40] = 2560
#define OFF_X2P  76288          // f32 [8][32] = 1024
#define OFF_S2   77312          // f32 [32]
#define OFF_C2   77440          // f32 [32]
#define OFF_ASUM 77568          // f32 [2][32]
#define LDS_TOTAL 77824

// xbuf layout: byte(d,n) = d*80 + (((n>>3) ^ (d&3))<<4) + (n&7)*2
// (R8 layout — best measured. Do NOT touch the swizzle algebra: two
//  variants (R9 8B-halfchunk, R10 +((d>>3)&3)) both regressed 14-22 µs
//  via codegen shifts despite equal-or-better theoretical bank spread.)

typedef unsigned short u16;
typedef __attribute__((ext_vector_type(8))) short short8v;
typedef __attribute__((ext_vector_type(4))) float f32x4;

#define SYNCL() asm volatile("s_waitcnt lgkmcnt(0)\n\ts_barrier" ::: "memory")

__device__ __forceinline__ unsigned f2bf(float f) {
    union { float f; unsigned u; } v; v.f = f;
    unsigned r = v.u + 0x7fff + ((v.u >> 16) & 1);   // RNE
    return r >> 16;
}

// ---------------- K1: fused, staggered staging, folded c-prep ------------
template <typename PART>
__global__ __launch_bounds__(512, 4)
void k1_fused(const float* __restrict__ x, const float* __restrict__ cw,
              const float* __restrict__ scale,
              float* __restrict__ ws_asum, PART* __restrict__ ws_e) {
    extern __shared__ char smem[];
    u16*   xbuf    = (u16*)(smem + OFF_XBUF);
    u16*   c_lds   = (u16*)(smem + OFF_CLDS);
    u16*   a_t     = (u16*)(smem + OFF_AT);
    float* x2_part = (float*)(smem + OFF_X2P);
    float* s2_l    = (float*)(smem + OFF_S2);
    float* c2_l    = (float*)(smem + OFF_C2);
    float* asum_p  = (float*)(smem + OFF_ASUM);

    const int t = threadIdx.x;
    const int l = t & 63, w = t >> 6;        // lane, wave (8 waves)
    const int g = l >> 4, li = l & 15;       // 16-lane group, group-lane
    const int blk = blockIdx.x;
    const int b = blk >> 5, grp = blk & 31;
    const int n0 = grp * 128;
    const float* xg = x + (size_t)b * DD * NN + n0;

    // staging geometry: wave w owns rows [64w, 64w+64)
    const int lr = l >> 3;                   // row-subgroup 0..7
    const int lc = l & 7;                    // 16B fp32 col-group (4 n)
    const int cp = lc >> 1, lo = lc & 1;     // chunk + 8B half within chunk
    const float* xrow = xg + (size_t)(w * 64 + lr) * NN + lc * 4;
    // per-thread constant swizzled write offset: row r = w*64 + 8j + lr
    const int wswz = ((cp ^ (lr & 3)) << 4) | (lo << 3);

    // ---- prologue: c-row loads first ----
    const int ck = t >> 4, cseg = t & 15;    // 16 threads per k-row
    float4 cv[8];
    {
        const float* crow = cw + ck * DD + cseg * 32;
#pragma unroll
        for (int j = 0; j < 8; ++j) cv[j] = *(const float4*)(crow + 4 * j);
    }

    // ---- issue subtile-0 x loads (two halves) ----
    float4 vaA[4], vaB[4];
#pragma unroll
    for (int j = 0; j < 4; ++j) vaA[j] = *(const float4*)(xrow + (size_t)(j * 8) * NN);
#pragma unroll
    for (int j = 0; j < 4; ++j) vaB[j] = *(const float4*)(xrow + (size_t)((j + 4) * 8) * NN);

    // ---- stage c -> c_lds (chunk-swizzled) + c2 via 16-lane reduce ----
    {
        float c2p = 0.f;
#pragma unroll
        for (int j = 0; j < 8; ++j)
            c2p += cv[j].x * cv[j].x + cv[j].y * cv[j].y
                 + cv[j].z * cv[j].z + cv[j].w * cv[j].w;
#pragma unroll
        for (int j = 0; j < 4; ++j) {
            uint4 pk;
            asm("v_cvt_pk_bf16_f32 %0, %1, %2" : "=v"(pk.x) : "v"(cv[2*j].x),   "v"(cv[2*j].y));
            asm("v_cvt_pk_bf16_f32 %0, %1, %2" : "=v"(pk.y) : "v"(cv[2*j].z),   "v"(cv[2*j].w));
            asm("v_cvt_pk_bf16_f32 %0, %1, %2" : "=v"(pk.z) : "v"(cv[2*j+1].x), "v"(cv[2*j+1].y));
            asm("v_cvt_pk_bf16_f32 %0, %1, %2" : "=v"(pk.w) : "v"(cv[2*j+1].z), "v"(cv[2*j+1].w));
            const int dch = cseg * 4 + j;                 // 16B chunk idx 0..63
            *(uint4*)(smem + OFF_CLDS + ck * 1024 + ((dch ^ (ck & 7)) << 4)) = pk;
        }
        c2p += __shfl_xor(c2p, 1); c2p += __shfl_xor(c2p, 2);
        c2p += __shfl_xor(c2p, 4); c2p += __shfl_xor(c2p, 8);
        if ((l & 15) == 0) c2_l[ck] = c2p;
        if (t < KK) { float sc = scale[t]; s2_l[t] = sc * sc; }
    }

    f32x4 accB[8];
#pragma unroll
    for (int dt = 0; dt < 8; ++dt) accB[dt] = (f32x4){0.f, 0.f, 0.f, 0.f};
    float asum_acc[8] = {0.f, 0.f, 0.f, 0.f, 0.f, 0.f, 0.f, 0.f};

#pragma unroll
    for (int s = 0; s < SUBT; ++s) {
        // ---- convert vaA/vaB -> xbuf (swizzled b64 writes) + x2 partials ----
        {
            float p0 = 0, p1 = 0, p2 = 0, p3 = 0;
#pragma unroll
            for (int j = 0; j < 8; ++j) {
                float4 v = (j < 4) ? vaA[j] : vaB[j - 4];
                uint2 pk;
                asm("v_cvt_pk_bf16_f32 %0, %1, %2" : "=v"(pk.x) : "v"(v.x), "v"(v.y));
                asm("v_cvt_pk_bf16_f32 %0, %1, %2" : "=v"(pk.y) : "v"(v.z), "v"(v.w));
                const int r = w * 64 + j * 8 + lr;
                *(uint2*)(smem + OFF_XBUF + r * 80 + wswz) = pk;
                p0 += v.x * v.x; p1 += v.y * v.y;
                p2 += v.z * v.z; p3 += v.w * v.w;
            }
            p0 += __shfl_xor(p0, 8); p0 += __shfl_xor(p0, 16); p0 += __shfl_xor(p0, 32);
            p1 += __shfl_xor(p1, 8); p1 += __shfl_xor(p1, 16); p1 += __shfl_xor(p1, 32);
            p2 += __shfl_xor(p2, 8); p2 += __shfl_xor(p2, 16); p2 += __shfl_xor(p2, 32);
            p3 += __shfl_xor(p3, 8); p3 += __shfl_xor(p3, 16); p3 += __shfl_xor(p3, 32);
            if (lr == 0) {
                float4 p4 = {p0, p1, p2, p3};
                *(float4*)((char*)smem + OFF_X2P + w * 128 + lc * 16) = p4;
            }
        }
        SYNCL();   // 1: xbuf + x2_part visible (also gates c_lds/c2/s2 at s=0)

        // ---- issue next subtile's first-half loads (all waves, early) ----
        if (s < SUBT - 1) {
#pragma unroll
            for (int j = 0; j < 4; ++j)
                vaA[j] = *(const float4*)(xrow + (size_t)(j * 8) * NN + (s + 1) * TNS);
        }

        // ---- phase A + softmax fused (waves 0-1, boosted priority) ----
        if (w < 2) {
            __builtin_amdgcn_s_setprio(1);
            f32x4 accA0 = {0.f, 0.f, 0.f, 0.f}, accA1 = {0.f, 0.f, 0.f, 0.f};
            const int nloc = w * 16 + li;
            const int nc = nloc >> 3, nr = nloc & 7;
            for (int ch = 0; ch < 16; ++ch) {
                const int dbase = ch * 32 + g * 8;
                short8v bf;
#pragma unroll
                for (int j = 0; j < 8; ++j) {
                    const int d = dbase + j;
                    bf[j] = (short)xbuf[d * ROWX + ((nc ^ (d & 3)) << 3) + nr];
                }
                const int csw = ((ch * 4 + g) ^ (li & 7)) << 3;
                short8v a0 = *(const short8v*)(c_lds + li * DD + csw);
                short8v a1 = *(const short8v*)(c_lds + (16 + li) * DD + csw);
                accA0 = __builtin_amdgcn_mfma_f32_16x16x32_bf16(a0, bf, accA0, 0, 0, 0);
                accA1 = __builtin_amdgcn_mfma_f32_16x16x32_bf16(a1, bf, accA1, 0, 0, 0);
            }
            // softmax over k for column nloc
            float x2v = 0.f;
#pragma unroll
            for (int p = 0; p < 8; ++p) x2v += x2_part[p * 32 + nloc];
            float sl[8];
            float mx = -3.4e38f;
#pragma unroll
            for (int r = 0; r < 4; ++r) {
                float v0 = s2_l[4 * g + r]      * (x2v - 2.f * accA0[r] + c2_l[4 * g + r]);
                float v1 = s2_l[16 + 4 * g + r] * (x2v - 2.f * accA1[r] + c2_l[16 + 4 * g + r]);
                sl[r] = v0; sl[4 + r] = v1;
                mx = fmaxf(mx, fmaxf(v0, v1));
            }
            mx = fmaxf(mx, __shfl_xor(mx, 16));
            mx = fmaxf(mx, __shfl_xor(mx, 32));
            float sum = 0.f;
#pragma unroll
            for (int i = 0; i < 8; ++i) { sl[i] = __expf(sl[i] - mx); sum += sl[i]; }
            sum += __shfl_xor(sum, 16);
            sum += __shfl_xor(sum, 32);
            const float inv = 1.f / sum;
#pragma unroll
            for (int i = 0; i < 8; ++i) {
                float a = sl[i] * inv;
                int k = (i < 4) ? (4 * g + i) : (16 + 4 * g + (i - 4));
                a_t[k * ROWA + nloc] = (u16)f2bf(a);
                float ssum = a;
                ssum += __shfl_xor(ssum, 1); ssum += __shfl_xor(ssum, 2);
                ssum += __shfl_xor(ssum, 4); ssum += __shfl_xor(ssum, 8);
                asum_acc[i] += ssum;    // valid on li==0
            }
            __builtin_amdgcn_s_setprio(0);
        }

        // ---- issue next subtile's second-half loads (staggered) ----
        if (s < SUBT - 1) {
#pragma unroll
            for (int j = 0; j < 4; ++j)
                vaB[j] = *(const float4*)(xrow + (size_t)((j + 4) * 8) * NN + (s + 1) * TNS);
        }
        SYNCL();   // 2: a_t ready

        // ---- phase B (all 8 waves): e[k-tile][128 d per wave] += a . x^T ----
        {
            const int kt = w >> 2, dblk = w & 3;
            short8v af = *(const short8v*)(a_t + (kt * 16 + li) * ROWA + g * 8);
#pragma unroll
            for (int dt = 0; dt < 8; ++dt) {
                const int d = dblk * 128 + dt * 16 + li;
                short8v xf = *(const short8v*)(xbuf + d * ROWX + ((g ^ (d & 3)) << 3));
                accB[dt] = __builtin_amdgcn_mfma_f32_16x16x32_bf16(af, xf, accB[dt], 0, 0, 0);
            }
        }
        SYNCL();   // 3: xbuf free for next convert
    }

    // ---- asum -> ws ----
    if (w < 2 && li == 0) {
#pragma unroll
        for (int i = 0; i < 8; ++i) {
            int k = (i < 4) ? (4 * g + i) : (16 + 4 * g + (i - 4));
            asum_p[w * KK + k] = asum_acc[i];
        }
    }
    __syncthreads();
    if (t < KK) ws_asum[(size_t)blk * KK + t] = asum_p[t] + asum_p[KK + t];

    // ---- e partials -> ws (once per block) ----
    {
        const int kt = w >> 2, dblk = w & 3;
        const size_t ebase = (size_t)blk * KK * DD;
#pragma unroll
        for (int dt = 0; dt < 8; ++dt)
#pragma unroll
            for (int r = 0; r < 4; ++r) {
                int k = kt * 16 + 4 * g + r;
                int d = dblk * 128 + dt * 16 + li;
                ws_e[ebase + (size_t)k * DD + d] = (PART)(accB[dt][r]);
            }
    }
}

// ---------------- K2: reduce 32 partials, subtract asum*c ----------------
__global__ void k2_reduce_h(const __half2* __restrict__ ws_e, const float* __restrict__ ws_asum,
                            const float* __restrict__ cw, float* __restrict__ out) {
    int tid = blockIdx.x * blockDim.x + threadIdx.x;   // 131072
    int d2 = tid & 255;
    int k = (tid >> 8) & (KK - 1);
    int b = tid >> 13;
    const __half2* pe = ws_e + ((size_t)(b * NGRP) * KK + k) * 256 + d2;
    const float* pa = ws_asum + b * NGRP * KK + k;
    float s0 = 0.f, s1 = 0.f, as = 0.f;
#pragma unroll
    for (int tl = 0; tl < NGRP; ++tl) {
        float2 f = __half22float2(pe[(size_t)tl * KK * 256]);
        s0 += f.x; s1 += f.y;
        as += pa[tl * KK];
    }
    int d = d2 * 2;
    float c0 = cw[k * DD + d], c1 = cw[k * DD + d + 1];
    float2 o; o.x = s0 - as * c0; o.y = s1 - as * c1;
    *(float2*)(out + ((size_t)(b * KK + k) * DD + d)) = o;
}

__global__ void k2_reduce_f(const float* __restrict__ ws_e, const float* __restrict__ ws_asum,
                            const float* __restrict__ cw, float* __restrict__ out) {
    int tid = blockIdx.x * blockDim.x + threadIdx.x;   // 262144
    int d = tid & (DD - 1);
    int k = (tid >> 9) & (KK - 1);
    int b = tid >> 14;
    float s = 0.f, as = 0.f;
#pragma unroll
    for (int tl = 0; tl < NGRP; ++tl) {
        int blk = b * NGRP + tl;
        s += ws_e[((size_t)blk * KK + k) * DD + d];
        as += ws_asum[(size_t)blk * KK + k];
    }
    out[tid] = s - as * cw[k * DD + d];
}

extern "C" void kernel_launch(void* const* d_in, const int* in_sizes, int n_in,
                              void* d_out, int out_size, void* d_ws, size_t ws_size,
                              hipStream_t stream) {
    const float* x = (const float*)d_in[0];
    const float* cw = (const float*)d_in[1];
    const float* scale = (const float*)d_in[2];
    float* out = (float*)d_out;

    char* ws = (char*)d_ws;
    float* ws_asum = (float*)ws;                // 512*32*4 = 65536 B
    char*  e_ptr   = ws + 65536;

    const size_t need_h = 65536 + (size_t)NBLK * KK * DD * sizeof(__half);

    if (ws_size >= need_h) {
        k1_fused<__half><<<NBLK, 512, LDS_TOTAL, stream>>>(x, cw, scale, ws_asum, (__half*)e_ptr);
        k2_reduce_h<<<(BB * KK * 256) / 256, 256, 0, stream>>>((const __half2*)e_ptr, ws_asum, cw, out);
    } else {
        k1_fused<float><<<NBLK, 512, LDS_TOTAL, stream>>>(x, cw, scale, ws_asum, (float*)e_ptr);
        k2_reduce_f<<<(BB * KK * DD) / 256, 256, 0, stream>>>((const float*)e_ptr, ws_asum, cw, out);
    }
}